// Round 5
// baseline (525.220 us; speedup 1.0000x reference)
//
#include <hip/hip_runtime.h>
#include <stdint.h>

typedef unsigned short u16;

#define GAS __attribute__((address_space(1)))
#define LAS __attribute__((address_space(3)))

typedef __bf16 bf16x8 __attribute__((ext_vector_type(8)));
typedef float f32x4 __attribute__((ext_vector_type(4)));

// B=4, T=2048, D_IN=D_OUT=2048. M = 8192, K = 6144, N = 2048.
// fp32 I/O; GEMM internally bf16 MFMA with per-row-per-segment gate scaling.
// ws layout: Z bf16 [8192 x 6144] (96 MB, UNSCALED [x|s|d])
//          | Wcat bf16 [2048 x 6144] (24 MB; first 2 MB doubles as scan-carry
//            scratch before pack_w runs)
//          | logits/gates fp32 [8192 x 3] (96 KB)

__device__ inline u16 f2b(float f) {
    uint32_t x = __float_as_uint(f);
    uint32_t r = (x + 0x7fffu + ((x >> 16) & 1u)) >> 16;
    return (u16)r;
}

__device__ inline void load8f(float* v, const float* p) {
    float4 a = *(const float4*)p;
    float4 b = *(const float4*)(p + 4);
    v[0] = a.x; v[1] = a.y; v[2] = a.z; v[3] = a.w;
    v[4] = b.x; v[5] = b.y; v[6] = b.z; v[7] = b.w;
}

__device__ inline void store8b(u16* p, const float* v) {
    uint4 u;
    u.x = (uint32_t)f2b(v[0]) | ((uint32_t)f2b(v[1]) << 16);
    u.y = (uint32_t)f2b(v[2]) | ((uint32_t)f2b(v[3]) << 16);
    u.z = (uint32_t)f2b(v[4]) | ((uint32_t)f2b(v[5]) << 16);
    u.w = (uint32_t)f2b(v[6]) | ((uint32_t)f2b(v[7]) << 16);
    *(uint4*)p = u;
}

__device__ inline float sigmoidf(float v) { return 1.f / (1.f + __expf(-v)); }

__device__ inline float pow64f(float a) {
    float p = a * a;
    p = p * p;
    p = p * p;
    p = p * p;
    p = p * p;
    return p * p;
}

// ---------------------------------------------------------------------------
// pack Wp|Wi|Wd (fp32) into Wcat bf16 rows of 6144. Runs AFTER the scan
// passes (its output area holds scan carries until then).
// ---------------------------------------------------------------------------
__global__ __launch_bounds__(256) void pack_w(
    const float* __restrict__ Wp, const float* __restrict__ Wi,
    const float* __restrict__ Wd, u16* __restrict__ Wcat)
{
    int i = (blockIdx.x * 256 + threadIdx.x) * 8;
    int seg = i >> 22;
    int j = i & 4194303;
    const float* src = (seg == 0) ? Wp : (seg == 1) ? Wi : Wd;
    int o = j >> 11;
    int c = j & 2047;
    float v[8];
    load8f(v, src + j);
    store8b(Wcat + (size_t)o * 6144 + seg * 2048 + c, v);
}

// ---------------------------------------------------------------------------
// Scan pass 1: local 64-step scans, zero carry; store end states to carries.
// carries layout: [plane(2)][b(4)][c(32)][d(2048)] fp32.
// ---------------------------------------------------------------------------
__global__ __launch_bounds__(256) void scan_pass1(
    const float* __restrict__ x, const float* __restrict__ alog,
    const float* __restrict__ blog, float* __restrict__ carries)
{
    const int d = blockIdx.x * 256 + threadIdx.x;
    const int c = blockIdx.y;
    const int b = blockIdx.z;
    const float alpha = sigmoidf(alog[d]);
    const float beta  = sigmoidf(blog[d]);
    const float oma = 1.f - alpha, omb = 1.f - beta;
    const float* xp = x + ((size_t)b * 2048 + c * 64) * 2048 + d;
    float xprev = (c == 0) ? 0.f : xp[-2048];
    float s = 0.f, dd = 0.f;
    #pragma unroll 8
    for (int t = 0; t < 64; ++t) {
        float xf = xp[(size_t)t * 2048];
        s = alpha * s + oma * xf;
        dd = beta * dd + omb * (xf - xprev);
        xprev = xf;
    }
    carries[((0 * 4 + b) * 32 + c) * 2048 + d] = s;
    carries[((1 * 4 + b) * 32 + c) * 2048 + d] = dd;
}

// ---------------------------------------------------------------------------
// Scan pass 2: combine 32 chunk carries per (b,d) into input carries.
// ---------------------------------------------------------------------------
__global__ __launch_bounds__(256) void scan_pass2(
    const float* __restrict__ alog, const float* __restrict__ blog,
    float* __restrict__ carries)
{
    const int g = blockIdx.x * 256 + threadIdx.x;
    const int b = g >> 11;
    const int d = g & 2047;
    const float aL = pow64f(sigmoidf(alog[d]));
    const float bL = pow64f(sigmoidf(blog[d]));
    float sIn = 0.f, dIn = 0.f;
    for (int c = 0; c < 32; ++c) {
        float* sp = carries + ((0 * 4 + b) * 32 + c) * 2048 + d;
        float* dp = carries + ((1 * 4 + b) * 32 + c) * 2048 + d;
        float sl = *sp, dl = *dp;
        *sp = sIn; *dp = dIn;
        sIn = sl + aL * sIn;
        dIn = dl + bL * dIn;
    }
}

// ---------------------------------------------------------------------------
// Scan pass 3: exact scan per chunk from carry. Writes UNSCALED bf16 x,s,d
// into Z segs 0,1,2 AND accumulates gate logits (fp32 features, per-wave
// butterfly reduce + atomicAdd). logits must be zeroed beforehand.
// ---------------------------------------------------------------------------
__global__ __launch_bounds__(256) void scan_pass3(
    const float* __restrict__ x, const float* __restrict__ alog,
    const float* __restrict__ blog, const float* __restrict__ Wg,
    const float* __restrict__ carries, u16* __restrict__ Z,
    float* __restrict__ logits)
{
    const int d = blockIdx.x * 256 + threadIdx.x;
    const int c = blockIdx.y;
    const int b = blockIdx.z;
    const float alpha = sigmoidf(alog[d]);
    const float beta  = sigmoidf(blog[d]);
    const float oma = 1.f - alpha, omb = 1.f - beta;
    const float w0x = Wg[d],         w0s = Wg[2048 + d],         w0d = Wg[4096 + d];
    const float w1x = Wg[6144 + d],  w1s = Wg[6144 + 2048 + d],  w1d = Wg[6144 + 4096 + d];
    const float w2x = Wg[12288 + d], w2s = Wg[12288 + 2048 + d], w2d = Wg[12288 + 4096 + d];
    const float* xp = x + ((size_t)b * 2048 + c * 64) * 2048 + d;
    u16* zp = Z + ((size_t)b * 2048 + c * 64) * 6144 + d;
    float s  = carries[((0 * 4 + b) * 32 + c) * 2048 + d];
    float dd = carries[((1 * 4 + b) * 32 + c) * 2048 + d];
    float xprev = (c == 0) ? 0.f : xp[-2048];
    const int rowbase = b * 2048 + c * 64;
    const int lane = threadIdx.x & 63;
    #pragma unroll 4
    for (int t = 0; t < 64; ++t) {
        float xf = xp[(size_t)t * 2048];
        s = alpha * s + oma * xf;
        dd = beta * dd + omb * (xf - xprev);
        xprev = xf;
        size_t zo = (size_t)t * 6144;
        zp[zo]        = f2b(xf);
        zp[zo + 2048] = f2b(s);
        zp[zo + 4096] = f2b(dd);
        float c0 = w0x * xf + w0s * s + w0d * dd;
        float c1 = w1x * xf + w1s * s + w1d * dd;
        float c2 = w2x * xf + w2s * s + w2d * dd;
        #pragma unroll
        for (int off = 32; off > 0; off >>= 1) {
            c0 += __shfl_xor(c0, off);
            c1 += __shfl_xor(c1, off);
            c2 += __shfl_xor(c2, off);
        }
        if (lane == 0) {
            int row = rowbase + t;
            atomicAdd(&logits[row * 3 + 0], c0);
            atomicAdd(&logits[row * 3 + 1], c1);
            atomicAdd(&logits[row * 3 + 2], c2);
        }
    }
}

// ---------------------------------------------------------------------------
// Softmax: logits -> gates in place (adds W_gate_b). 8192 rows.
// ---------------------------------------------------------------------------
__global__ __launch_bounds__(256) void softmax_k(
    float* __restrict__ logits, const float* __restrict__ Wgb)
{
    int r = blockIdx.x * 256 + threadIdx.x;
    float l0 = logits[r * 3 + 0] + Wgb[0];
    float l1 = logits[r * 3 + 1] + Wgb[1];
    float l2 = logits[r * 3 + 2] + Wgb[2];
    float m = fmaxf(l0, fmaxf(l1, l2));
    float e0 = __expf(l0 - m), e1 = __expf(l1 - m), e2 = __expf(l2 - m);
    float inv = 1.f / (e0 + e1 + e2);
    logits[r * 3 + 0] = e0 * inv;
    logits[r * 3 + 1] = e1 * inv;
    logits[r * 3 + 2] = e2 * inv;
}

// ---------------------------------------------------------------------------
// GEMM: Y = sum_seg g_seg(row) * (Z_seg @ Wcat_seg^T) + bias.
// bf16 MFMA, 128x128 tile, BK=64, 3 segments x 32 kt. Gate scaling by
// accumulator telescoping: acc *= g0/g1 after seg0, *= g1/g2 after seg1,
// epilogue *g2 (ratios <= ~1e4, fp32-safe). Swizzled LDS (conflict-free,
// verified R3). __launch_bounds__(256,3): keep 3 blocks/CU co-resident.
// ---------------------------------------------------------------------------
__global__ __launch_bounds__(256, 3) void gemm_kernel(
    const u16* __restrict__ Z, const u16* __restrict__ Wcat,
    const float* __restrict__ gates, const float* __restrict__ bias,
    float* __restrict__ out)
{
    __shared__ u16 a_sh[128 * 64];
    __shared__ u16 b_sh[128 * 64];

    const int tid = threadIdx.x;
    const int bm = blockIdx.y * 128;
    const int bn = blockIdx.x * 128;

    const int srow = tid >> 3;                       // 0..31
    const int scq  = tid & 7;
    const int ssub = (scq ^ (srow & 7)) * 8;
    const u16* aglob = Z + (size_t)(bm + srow) * 6144 + ssub;
    const u16* bglob = Wcat + (size_t)(bn + srow) * 6144 + ssub;
    u16* alds[4];
    u16* blds[4];
    #pragma unroll
    for (int c = 0; c < 4; ++c) {
        alds[c] = a_sh + c * 2048 + tid * 8;
        blds[c] = b_sh + c * 2048 + tid * 8;
    }

    const int lane = tid & 63;
    const int wv = tid >> 6;
    const int wm = (wv & 1) * 64;
    const int wn = (wv >> 1) * 64;
    const int fr = lane & 15;
    const int fq = lane >> 4;

    // Per-row gates for this thread's 16 accumulator rows.
    float r01[16], r12[16], g2v[16];
    #pragma unroll
    for (int i = 0; i < 4; ++i) {
        #pragma unroll
        for (int r = 0; r < 4; ++r) {
            int row = bm + wm + i * 16 + fq * 4 + r;
            float g0 = gates[row * 3 + 0];
            float g1 = gates[row * 3 + 1];
            float g2 = gates[row * 3 + 2];
            int idx = i * 4 + r;
            r01[idx] = g0 / g1;
            r12[idx] = g1 / g2;
            g2v[idx] = g2;
        }
    }

    f32x4 acc[4][4] = {};

    for (int seg = 0; seg < 3; ++seg) {
        for (int kt = 0; kt < 32; ++kt) {
            const int k0 = seg * 2048 + kt * 64;
            #pragma unroll
            for (int c = 0; c < 4; ++c)
                __builtin_amdgcn_global_load_lds(
                    (const GAS uint32_t*)(aglob + (size_t)c * 32 * 6144 + k0),
                    (LAS uint32_t*)alds[c], 16, 0, 0);
            #pragma unroll
            for (int c = 0; c < 4; ++c)
                __builtin_amdgcn_global_load_lds(
                    (const GAS uint32_t*)(bglob + (size_t)c * 32 * 6144 + k0),
                    (LAS uint32_t*)blds[c], 16, 0, 0);
            __syncthreads();

            #pragma unroll
            for (int h = 0; h < 2; ++h) {
                bf16x8 avf[4], bvf[4];
                #pragma unroll
                for (int i = 0; i < 4; ++i) {
                    int row = wm + i * 16 + fr;
                    int ch = (fq + 4 * h) ^ (row & 7);
                    avf[i] = *(const bf16x8*)(a_sh + row * 64 + ch * 8);
                }
                #pragma unroll
                for (int j = 0; j < 4; ++j) {
                    int row = wn + j * 16 + fr;
                    int ch = (fq + 4 * h) ^ (row & 7);
                    bvf[j] = *(const bf16x8*)(b_sh + row * 64 + ch * 8);
                }
                #pragma unroll
                for (int i = 0; i < 4; ++i)
                    #pragma unroll
                    for (int j = 0; j < 4; ++j)
                        acc[i][j] = __builtin_amdgcn_mfma_f32_16x16x32_bf16(
                            avf[i], bvf[j], acc[i][j], 0, 0, 0);
            }
            __syncthreads();
        }
        if (seg < 2) {
            #pragma unroll
            for (int i = 0; i < 4; ++i)
                #pragma unroll
                for (int r = 0; r < 4; ++r) {
                    float sc = (seg == 0) ? r01[i * 4 + r] : r12[i * 4 + r];
                    #pragma unroll
                    for (int j = 0; j < 4; ++j)
                        acc[i][j][r] *= sc;
                }
        }
    }

    #pragma unroll
    for (int j = 0; j < 4; ++j) {
        const int col = bn + wn + j * 16 + fr;
        const float bv = bias[col];
        #pragma unroll
        for (int i = 0; i < 4; ++i) {
            const int row0 = bm + wm + i * 16 + fq * 4;
            #pragma unroll
            for (int r = 0; r < 4; ++r)
                out[(size_t)(row0 + r) * 2048 + col] =
                    acc[i][j][r] * g2v[i * 4 + r] + bv;
        }
    }
}

extern "C" void kernel_launch(void* const* d_in, const int* in_sizes, int n_in,
                              void* d_out, int out_size, void* d_ws, size_t ws_size,
                              hipStream_t stream) {
    const float* x    = (const float*)d_in[0];
    const float* Wp   = (const float*)d_in[1];
    const float* Wi   = (const float*)d_in[2];
    const float* Wd   = (const float*)d_in[3];
    const float* al   = (const float*)d_in[4];
    const float* bl   = (const float*)d_in[5];
    const float* Wg   = (const float*)d_in[6];
    const float* Wgb  = (const float*)d_in[7];
    const float* bias = (const float*)d_in[8];
    float* out = (float*)d_out;

    u16* Z       = (u16*)d_ws;                                     // 96 MB
    u16* Wcat    = (u16*)((char*)d_ws + (size_t)8192 * 6144 * 2);  // +24 MB
    float* carries = (float*)Wcat;                                 // 2 MB, dead before pack_w
    float* logits  = (float*)((char*)d_ws + (size_t)10240 * 6144 * 2); // +96 KB

    hipMemsetAsync(logits, 0, (size_t)8192 * 3 * sizeof(float), stream);
    scan_pass1<<<dim3(8, 32, 4), 256, 0, stream>>>(x, al, bl, carries);
    scan_pass2<<<32, 256, 0, stream>>>(al, bl, carries);
    scan_pass3<<<dim3(8, 32, 4), 256, 0, stream>>>(x, al, bl, Wg, carries, Z, logits);
    softmax_k<<<32, 256, 0, stream>>>(logits, Wgb);
    pack_w<<<6144, 256, 0, stream>>>(Wp, Wi, Wd, Wcat);
    gemm_kernel<<<dim3(16, 64), 256, 0, stream>>>(Z, Wcat, logits, bias, out);
}